// Round 3
// baseline (187.151 us; speedup 1.0000x reference)
//
#include <hip/hip_runtime.h>

// SinePredictor:
//   s = h[edges[0]]; o = h[edges[1]]            [E,128] gathers
//   score = sin(s-o) @ W.T + b                  [E,1]
//   score = softmax over consecutive pairs      [E/2,2] -> [E,1]
//   out = concat(score, score > 0.5)            2*E floats
//
// Round 2 evidence: FETCH_SIZE pinned at 306 MB (== compulsory-miss floor for
// random fp32 row gathers) at ~3.3 TB/s on the L2-miss path; time did not move
// when VALUBusy dropped 85->36%. => fabric/byte-bound. Round 3: gather bf16.
//
// Phase 0: cast h -> bf16 in workspace (streaming), zero borderline counter.
// Phase 1: score all pairs from bf16 rows (256 B/row instead of 512 B).
//          Flag pairs with |x1-x2| < TAU (bf16-path logit error <= ~0.028
//          worst-case; TAU=0.05) into a list.
// Phase 2: recompute flagged pairs (~13k expected) with fp32 gathers — exact
//          same numerics as the round-2 kernel that passed — and overwrite.
// Mask output (score>0.5) therefore always carries the fp32 sign.

constexpr int   DIMS = 128;
constexpr float TAU  = 0.05f;

__device__ __forceinline__ float bf2f(unsigned short u) {
    union { unsigned int i; float f; } c;
    c.i = ((unsigned int)u) << 16;
    return c.f;
}

__device__ __forceinline__ unsigned short f2bf_rne(float f) {
    union { float f; unsigned int i; } c;
    c.f = f;
    unsigned int r = c.i + 0x7FFFu + ((c.i >> 16) & 1u);
    return (unsigned short)(r >> 16);
}

// ---------------- Phase 0: h (fp32) -> hb (bf16), zero counter --------------
__global__ __launch_bounds__(256) void cast_h_kernel(
    const float* __restrict__ h, unsigned short* __restrict__ hb,
    int n_vec4, int* __restrict__ counter)
{
    if (blockIdx.x == 0 && threadIdx.x == 0) *counter = 0;
    int i = blockIdx.x * blockDim.x + threadIdx.x;
    const int stride = gridDim.x * blockDim.x;
    for (; i < n_vec4; i += stride) {
        const float4 v = reinterpret_cast<const float4*>(h)[i];
        ushort4 o;
        o.x = f2bf_rne(v.x); o.y = f2bf_rne(v.y);
        o.z = f2bf_rne(v.z); o.w = f2bf_rne(v.w);
        reinterpret_cast<ushort4*>(hb)[i] = o;
    }
}

// ---------------- Phase 1: bf16 scoring + borderline detect -----------------
// Wave = 4 consecutive pairs. lanes 0..31 -> even edge, 32..63 -> odd edge.
// Each lane loads ushort4 (8 B) of the 256 B bf16 row.
__global__ __launch_bounds__(256) void score_bf16_kernel(
    const unsigned short* __restrict__ hb,
    const int*   __restrict__ edges,   // [2, E] int32
    const float* __restrict__ W,       // [1, 128]
    const float* __restrict__ b,
    float*       __restrict__ out,     // [2*E]: scores then mask
    int n_edges,
    int* __restrict__ counter, int* __restrict__ list, int list_cap)
{
    const int lane = threadIdx.x & 63;
    const int sub  = lane & 31;
    const int half = lane >> 5;
    const int waves_per_block = blockDim.x >> 6;
    const int wave_id = blockIdx.x * waves_per_block + (threadIdx.x >> 6);
    const int n_waves = gridDim.x * waves_per_block;
    const int n_pairs = n_edges >> 1;
    const int n_chunk = (n_pairs + 3) >> 2;

    const float4 w4  = reinterpret_cast<const float4*>(W)[sub];
    const float bias = b[0];

    for (int c = wave_id; c < n_chunk; c += n_waves) {
        const int base_pair = c * 4;
        float x[4];
        bool  valid[4];

        #pragma unroll
        for (int u = 0; u < 4; ++u) {
            const int pair = base_pair + u;
            valid[u] = pair < n_pairs;
            x[u] = 0.0f;
            if (valid[u]) {
                const int e   = 2 * pair + half;
                const int src = edges[e];
                const int obj = edges[n_edges + e];
                const ushort4 sv = reinterpret_cast<const ushort4*>(
                                       hb + (size_t)src * DIMS)[sub];
                const ushort4 ov = reinterpret_cast<const ushort4*>(
                                       hb + (size_t)obj * DIMS)[sub];
                x[u] = __sinf(bf2f(sv.x) - bf2f(ov.x)) * w4.x
                     + __sinf(bf2f(sv.y) - bf2f(ov.y)) * w4.y
                     + __sinf(bf2f(sv.z) - bf2f(ov.z)) * w4.z
                     + __sinf(bf2f(sv.w) - bf2f(ov.w)) * w4.w;
            }
        }

        #pragma unroll
        for (int u = 0; u < 4; ++u) {
            #pragma unroll
            for (int m = 16; m >= 1; m >>= 1)
                x[u] += __shfl_xor(x[u], m, 64);
            x[u] += bias;
        }

        #pragma unroll
        for (int u = 0; u < 4; ++u) {
            if (!valid[u]) continue;
            const int e      = 2 * (base_pair + u) + half;
            const float other = __shfl_xor(x[u], 32, 64);
            const float mx   = fmaxf(x[u], other);
            const float es   = __expf(x[u] - mx);
            const float eo   = __expf(other - mx);
            const float p    = es / (es + eo);
            if (sub == 0) {
                out[e]           = p;
                out[n_edges + e] = (p > 0.5f) ? 1.0f : 0.0f;
            }
            if (lane == 0 && fabsf(x[u] - other) < TAU) {
                const int id = atomicAdd(counter, 1);
                if (id < list_cap) list[id] = base_pair + u;
            }
        }
    }
}

// ---------------- Phase 2: fp32 fixup of borderline pairs -------------------
__global__ __launch_bounds__(256) void fixup_kernel(
    const float* __restrict__ h,
    const int*   __restrict__ edges,
    const float* __restrict__ W,
    const float* __restrict__ b,
    float*       __restrict__ out,
    int n_edges,
    const int* __restrict__ counter, const int* __restrict__ list, int list_cap)
{
    const int lane = threadIdx.x & 63;
    const int sub  = lane & 31;
    const int half = lane >> 5;
    const int waves_per_block = blockDim.x >> 6;
    const int wave_id = blockIdx.x * waves_per_block + (threadIdx.x >> 6);
    const int n_waves = gridDim.x * waves_per_block;

    int cnt = *counter;
    if (cnt > list_cap) cnt = list_cap;

    const float4 w4  = reinterpret_cast<const float4*>(W)[sub];
    const float bias = b[0];

    for (int i = wave_id; i < cnt; i += n_waves) {
        const int pair = list[i];
        const int e    = 2 * pair + half;
        const int src  = edges[e];
        const int obj  = edges[n_edges + e];
        const float4 s4 = reinterpret_cast<const float4*>(h + (size_t)src * DIMS)[sub];
        const float4 o4 = reinterpret_cast<const float4*>(h + (size_t)obj * DIMS)[sub];
        float part = __sinf(s4.x - o4.x) * w4.x
                   + __sinf(s4.y - o4.y) * w4.y
                   + __sinf(s4.z - o4.z) * w4.z
                   + __sinf(s4.w - o4.w) * w4.w;
        #pragma unroll
        for (int m = 16; m >= 1; m >>= 1)
            part += __shfl_xor(part, m, 64);
        const float x     = part + bias;
        const float other = __shfl_xor(x, 32, 64);
        const float mx    = fmaxf(x, other);
        const float es    = __expf(x - mx);
        const float eo    = __expf(other - mx);
        const float p     = es / (es + eo);
        if (sub == 0) {
            out[e]           = p;
            out[n_edges + e] = (p > 0.5f) ? 1.0f : 0.0f;
        }
    }
}

// ---------------- Fallback: round-2 fp32 single kernel ----------------------
__global__ __launch_bounds__(256) void sine_predictor_fp32_kernel(
    const float* __restrict__ h,
    const int*   __restrict__ edges,
    const float* __restrict__ W,
    const float* __restrict__ b,
    float*       __restrict__ out,
    int n_edges)
{
    const int lane = threadIdx.x & 63;
    const int sub  = lane & 31;
    const int half = lane >> 5;
    const int waves_per_block = blockDim.x >> 6;
    const int wave_id = blockIdx.x * waves_per_block + (threadIdx.x >> 6);
    const int n_waves = gridDim.x * waves_per_block;
    const int n_pairs = n_edges >> 1;

    const float4 w4  = reinterpret_cast<const float4*>(W)[sub];
    const float bias = b[0];

    for (int pair = wave_id; pair < n_pairs; pair += n_waves) {
        const int e   = 2 * pair + half;
        const int src = edges[e];
        const int obj = edges[n_edges + e];
        const float4 s4 = reinterpret_cast<const float4*>(h + (size_t)src * DIMS)[sub];
        const float4 o4 = reinterpret_cast<const float4*>(h + (size_t)obj * DIMS)[sub];
        float part = __sinf(s4.x - o4.x) * w4.x
                   + __sinf(s4.y - o4.y) * w4.y
                   + __sinf(s4.z - o4.z) * w4.z
                   + __sinf(s4.w - o4.w) * w4.w;
        #pragma unroll
        for (int m = 16; m >= 1; m >>= 1)
            part += __shfl_xor(part, m, 64);
        const float x     = part + bias;
        const float other = __shfl_xor(x, 32, 64);
        const float mx    = fmaxf(x, other);
        const float es    = __expf(x - mx);
        const float eo    = __expf(other - mx);
        const float p     = es / (es + eo);
        if (sub == 0) {
            out[e]           = p;
            out[n_edges + e] = (p > 0.5f) ? 1.0f : 0.0f;
        }
    }
}

extern "C" void kernel_launch(void* const* d_in, const int* in_sizes, int n_in,
                              void* d_out, int out_size, void* d_ws, size_t ws_size,
                              hipStream_t stream) {
    const float* h     = (const float*)d_in[0];
    const int*   edges = (const int*)d_in[1];
    const float* W     = (const float*)d_in[2];
    const float* b     = (const float*)d_in[3];
    float*       out   = (float*)d_out;

    const int n_edges = in_sizes[1] / 2;        // edges is [2, E]
    const int n_nodes = in_sizes[0] / DIMS;

    const size_t hb_bytes = (size_t)n_nodes * DIMS * 2;  // bf16 copy of h
    const size_t need     = hb_bytes + 16 + (1u << 20);

    if (ws_size >= need) {
        unsigned short* hb = (unsigned short*)d_ws;
        int* counter = (int*)((char*)d_ws + hb_bytes);
        int* list    = (int*)((char*)d_ws + hb_bytes + 16);
        int list_cap = (int)((ws_size - hb_bytes - 16) / 4);
        if (list_cap > n_edges / 2) list_cap = n_edges / 2;

        cast_h_kernel<<<2048, 256, 0, stream>>>(h, hb, n_nodes * DIMS / 4, counter);
        score_bf16_kernel<<<2048, 256, 0, stream>>>(hb, edges, W, b, out, n_edges,
                                                    counter, list, list_cap);
        fixup_kernel<<<512, 256, 0, stream>>>(h, edges, W, b, out, n_edges,
                                              counter, list, list_cap);
    } else {
        sine_predictor_fp32_kernel<<<2048, 256, 0, stream>>>(h, edges, W, b, out, n_edges);
    }
}

// Round 4
// 183.702 us; speedup vs baseline: 1.0188x; 1.0188x over previous
//
#include <hip/hip_runtime.h>

// SinePredictor:
//   s = h[edges[0]]; o = h[edges[1]]            [E,128] gathers
//   score = sin(s-o) @ W.T + b                  [E,1]
//   score = softmax over consecutive pairs      [E/2,2] -> [E,1]
//   out = concat(score, score > 0.5)            2*E floats
//
// Evidence so far:
//   R2 fp32 (wave=1 pair, 16B/lane): 97 us, FETCH 306 MB, VALU 36%.
//   R3 bf16 (wave=4 pairs, 8B/lane dwordx2, 4x unroll): 164 us, FETCH 139 MB.
//   -> NOT byte-bound (half bytes, slower). VGPR=20 both rounds: compiler
//      serialized loads (1+ vmcnt round-trip per pair). Latency-trip-bound.
// R4: bf16 rows (256 B) read by 16-lane quarter-waves at 16 B/lane (dwordx4).
//     One wave = 4 edges (2 pairs) = 2 row-load instrs (1 KB each). 2-chunk
//     unroll with all index loads then all row loads in distinct registers:
//     4 pairs per memory round-trip instead of 1.

constexpr int   DIMS = 128;
constexpr float TAU  = 0.05f;

__device__ __forceinline__ float blo(unsigned int u) {
    union { unsigned int i; float f; } c; c.i = u << 16; return c.f;
}
__device__ __forceinline__ float bhi(unsigned int u) {
    union { unsigned int i; float f; } c; c.i = u & 0xFFFF0000u; return c.f;
}
__device__ __forceinline__ unsigned short f2bf_rne(float f) {
    union { float f; unsigned int i; } c; c.f = f;
    unsigned int r = c.i + 0x7FFFu + ((c.i >> 16) & 1u);
    return (unsigned short)(r >> 16);
}

// 8-element sin-dot from two 16B bf16 fragments (elements sub*8 .. sub*8+7).
__device__ __forceinline__ float dot8(const uint4 s, const uint4 o,
                                      const float4 wl, const float4 wh) {
    return __sinf(blo(s.x) - blo(o.x)) * wl.x
         + __sinf(bhi(s.x) - bhi(o.x)) * wl.y
         + __sinf(blo(s.y) - blo(o.y)) * wl.z
         + __sinf(bhi(s.y) - bhi(o.y)) * wl.w
         + __sinf(blo(s.z) - blo(o.z)) * wh.x
         + __sinf(bhi(s.z) - bhi(o.z)) * wh.y
         + __sinf(blo(s.w) - blo(o.w)) * wh.z
         + __sinf(bhi(s.w) - bhi(o.w)) * wh.w;
}

// ---------------- Phase 0: h (fp32) -> hb (bf16), zero counter --------------
__global__ __launch_bounds__(256) void cast_h_kernel(
    const float* __restrict__ h, unsigned short* __restrict__ hb,
    int n_vec4, int* __restrict__ counter)
{
    if (blockIdx.x == 0 && threadIdx.x == 0) *counter = 0;
    int i = blockIdx.x * blockDim.x + threadIdx.x;
    const int stride = gridDim.x * blockDim.x;
    for (; i < n_vec4; i += stride) {
        const float4 v = reinterpret_cast<const float4*>(h)[i];
        ushort4 o;
        o.x = f2bf_rne(v.x); o.y = f2bf_rne(v.y);
        o.z = f2bf_rne(v.z); o.w = f2bf_rne(v.w);
        reinterpret_cast<ushort4*>(hb)[i] = o;
    }
}

// ---------------- Phase 1: bf16 scoring + borderline detect -----------------
// Wave = 2 pairs (4 edges). quarter q = lane>>4 -> edge 4c+q.
// Each lane loads uint4 (16 B = 8 bf16) of its edge's s-row and o-row:
// 16 lanes cover the full 256 B row; one load instr covers 4 rows (1 KB).
__global__ __launch_bounds__(256) void score_bf16_kernel(
    const unsigned short* __restrict__ hb,
    const int*   __restrict__ edges,   // [2, E] int32
    const float* __restrict__ W,       // [1, 128]
    const float* __restrict__ b,
    float*       __restrict__ out,     // [2*E]: scores then mask
    int n_edges,
    int* __restrict__ counter, int* __restrict__ list, int list_cap)
{
    const int lane    = threadIdx.x & 63;
    const int sub     = lane & 15;     // position within 256 B row
    const int quarter = lane >> 4;     // which of the 4 edges
    const int wave_id = blockIdx.x * (blockDim.x >> 6) + (threadIdx.x >> 6);
    const int n_waves = gridDim.x * (blockDim.x >> 6);
    const int n_pairs = n_edges >> 1;
    const int n_ch    = (n_pairs + 1) >> 1;       // chunks of 2 pairs

    const float4 wl  = reinterpret_cast<const float4*>(W)[sub * 2 + 0];
    const float4 wh  = reinterpret_cast<const float4*>(W)[sub * 2 + 1];
    const float bias = b[0];

    for (int c = wave_id; c < n_ch; c += 2 * n_waves) {
        const int  c2   = c + n_waves;
        const bool has2 = c2 < n_ch;

        // ---- issue all index loads (4 independent dword loads) ----
        const int eA  = 4 * c + quarter;
        const int eAc = min(eA, n_edges - 1);
        const int eB  = has2 ? 4 * c2 + quarter : eAc;
        const int eBc = min(eB, n_edges - 1);

        const int srcA = edges[eAc];
        const int objA = edges[n_edges + eAc];
        const int srcB = edges[eBc];
        const int objB = edges[n_edges + eBc];

        // ---- issue all 4 row loads (distinct registers, stay in flight) ----
        const uint4 sA = *reinterpret_cast<const uint4*>(hb + (size_t)srcA * DIMS + sub * 8);
        const uint4 oA = *reinterpret_cast<const uint4*>(hb + (size_t)objA * DIMS + sub * 8);
        const uint4 sB = *reinterpret_cast<const uint4*>(hb + (size_t)srcB * DIMS + sub * 8);
        const uint4 oB = *reinterpret_cast<const uint4*>(hb + (size_t)objB * DIMS + sub * 8);

        float xA = dot8(sA, oA, wl, wh);
        float xB = dot8(sB, oB, wl, wh);

        // ---- reduce within each 16-lane quarter ----
        #pragma unroll
        for (int m = 8; m >= 1; m >>= 1) xA += __shfl_xor(xA, m, 64);
        #pragma unroll
        for (int m = 8; m >= 1; m >>= 1) xB += __shfl_xor(xB, m, 64);
        xA += bias;
        xB += bias;

        // ---- pair softmax: partner quarter is quarter^1 (xor lane 16) ----
        {
            const float other = __shfl_xor(xA, 16, 64);
            const float mx = fmaxf(xA, other);
            const float es = __expf(xA - mx);
            const float eo = __expf(other - mx);
            const float p  = es / (es + eo);
            if (sub == 0 && eA < n_edges) {
                out[eA]           = p;
                out[n_edges + eA] = (p > 0.5f) ? 1.0f : 0.0f;
            }
            if (sub == 0 && (quarter & 1) == 0 && eA + 1 < n_edges &&
                fabsf(xA - other) < TAU) {
                const int id = atomicAdd(counter, 1);
                if (id < list_cap) list[id] = eA >> 1;
            }
        }
        if (has2) {
            const float other = __shfl_xor(xB, 16, 64);
            const float mx = fmaxf(xB, other);
            const float es = __expf(xB - mx);
            const float eo = __expf(other - mx);
            const float p  = es / (es + eo);
            if (sub == 0 && eB < n_edges) {
                out[eB]           = p;
                out[n_edges + eB] = (p > 0.5f) ? 1.0f : 0.0f;
            }
            if (sub == 0 && (quarter & 1) == 0 && eB + 1 < n_edges &&
                fabsf(xB - other) < TAU) {
                const int id = atomicAdd(counter, 1);
                if (id < list_cap) list[id] = eB >> 1;
            }
        }
    }
}

// ---------------- Phase 2: fp32 fixup of borderline pairs -------------------
__global__ __launch_bounds__(256) void fixup_kernel(
    const float* __restrict__ h,
    const int*   __restrict__ edges,
    const float* __restrict__ W,
    const float* __restrict__ b,
    float*       __restrict__ out,
    int n_edges,
    const int* __restrict__ counter, const int* __restrict__ list, int list_cap)
{
    const int lane = threadIdx.x & 63;
    const int sub  = lane & 31;
    const int half = lane >> 5;
    const int wave_id = blockIdx.x * (blockDim.x >> 6) + (threadIdx.x >> 6);
    const int n_waves = gridDim.x * (blockDim.x >> 6);

    int cnt = *counter;
    if (cnt > list_cap) cnt = list_cap;

    const float4 w4  = reinterpret_cast<const float4*>(W)[sub];
    const float bias = b[0];

    for (int i = wave_id; i < cnt; i += n_waves) {
        const int pair = list[i];
        const int e    = 2 * pair + half;
        const int src  = edges[e];
        const int obj  = edges[n_edges + e];
        const float4 s4 = reinterpret_cast<const float4*>(h + (size_t)src * DIMS)[sub];
        const float4 o4 = reinterpret_cast<const float4*>(h + (size_t)obj * DIMS)[sub];
        float part = __sinf(s4.x - o4.x) * w4.x
                   + __sinf(s4.y - o4.y) * w4.y
                   + __sinf(s4.z - o4.z) * w4.z
                   + __sinf(s4.w - o4.w) * w4.w;
        #pragma unroll
        for (int m = 16; m >= 1; m >>= 1)
            part += __shfl_xor(part, m, 64);
        const float x     = part + bias;
        const float other = __shfl_xor(x, 32, 64);
        const float mx    = fmaxf(x, other);
        const float es    = __expf(x - mx);
        const float eo    = __expf(other - mx);
        const float p     = es / (es + eo);
        if (sub == 0) {
            out[e]           = p;
            out[n_edges + e] = (p > 0.5f) ? 1.0f : 0.0f;
        }
    }
}

// ---------------- Fallback: round-2 fp32 single kernel ----------------------
__global__ __launch_bounds__(256) void sine_predictor_fp32_kernel(
    const float* __restrict__ h,
    const int*   __restrict__ edges,
    const float* __restrict__ W,
    const float* __restrict__ b,
    float*       __restrict__ out,
    int n_edges)
{
    const int lane = threadIdx.x & 63;
    const int sub  = lane & 31;
    const int half = lane >> 5;
    const int wave_id = blockIdx.x * (blockDim.x >> 6) + (threadIdx.x >> 6);
    const int n_waves = gridDim.x * (blockDim.x >> 6);
    const int n_pairs = n_edges >> 1;

    const float4 w4  = reinterpret_cast<const float4*>(W)[sub];
    const float bias = b[0];

    for (int pair = wave_id; pair < n_pairs; pair += n_waves) {
        const int e   = 2 * pair + half;
        const int src = edges[e];
        const int obj = edges[n_edges + e];
        const float4 s4 = reinterpret_cast<const float4*>(h + (size_t)src * DIMS)[sub];
        const float4 o4 = reinterpret_cast<const float4*>(h + (size_t)obj * DIMS)[sub];
        float part = __sinf(s4.x - o4.x) * w4.x
                   + __sinf(s4.y - o4.y) * w4.y
                   + __sinf(s4.z - o4.z) * w4.z
                   + __sinf(s4.w - o4.w) * w4.w;
        #pragma unroll
        for (int m = 16; m >= 1; m >>= 1)
            part += __shfl_xor(part, m, 64);
        const float x     = part + bias;
        const float other = __shfl_xor(x, 32, 64);
        const float mx    = fmaxf(x, other);
        const float es    = __expf(x - mx);
        const float eo    = __expf(other - mx);
        const float p     = es / (es + eo);
        if (sub == 0) {
            out[e]           = p;
            out[n_edges + e] = (p > 0.5f) ? 1.0f : 0.0f;
        }
    }
}

extern "C" void kernel_launch(void* const* d_in, const int* in_sizes, int n_in,
                              void* d_out, int out_size, void* d_ws, size_t ws_size,
                              hipStream_t stream) {
    const float* h     = (const float*)d_in[0];
    const int*   edges = (const int*)d_in[1];
    const float* W     = (const float*)d_in[2];
    const float* b     = (const float*)d_in[3];
    float*       out   = (float*)d_out;

    const int n_edges = in_sizes[1] / 2;        // edges is [2, E]
    const int n_nodes = in_sizes[0] / DIMS;

    const size_t hb_bytes = (size_t)n_nodes * DIMS * 2;  // bf16 copy of h
    const size_t need     = hb_bytes + 16 + (1u << 20);

    if (ws_size >= need) {
        unsigned short* hb = (unsigned short*)d_ws;
        int* counter = (int*)((char*)d_ws + hb_bytes);
        int* list    = (int*)((char*)d_ws + hb_bytes + 16);
        int list_cap = (int)((ws_size - hb_bytes - 16) / 4);
        if (list_cap > n_edges / 2) list_cap = n_edges / 2;

        cast_h_kernel<<<2048, 256, 0, stream>>>(h, hb, n_nodes * DIMS / 4, counter);
        score_bf16_kernel<<<2048, 256, 0, stream>>>(hb, edges, W, b, out, n_edges,
                                                    counter, list, list_cap);
        fixup_kernel<<<512, 256, 0, stream>>>(h, edges, W, b, out, n_edges,
                                              counter, list, list_cap);
    } else {
        sine_predictor_fp32_kernel<<<2048, 256, 0, stream>>>(h, edges, W, b, out, n_edges);
    }
}

// Round 5
// 90.939 us; speedup vs baseline: 2.0580x; 2.0201x over previous
//
#include <hip/hip_runtime.h>

// SinePredictor:
//   s = h[edges[0]]; o = h[edges[1]]            [E,128] fp32 gathers
//   score = sin(s-o) @ W.T + b                  [E,1]
//   score = softmax over consecutive pairs      [E/2,2] -> [E,1]
//   out = concat(score, score > 0.5)            2*E floats
//
// Evidence ledger:
//   R2 fp32 d_in  (2 rows in flight/wave):  97 us, FETCH 306 MB (3.15 TB/s)
//   R3 bf16 d_ws:                          164 us, FETCH 139 MB (0.87 TB/s)
//   R4 bf16 d_ws (4 rows in flight/wave):  162 us, FETCH 143 MB (0.88 TB/s)
//   -> R3==R4 despite different structures: the d_ws bf16 copy (rewritten
//      every replay, L2-flushed at kernel boundary) reads at random-HBM
//      speed; d_in's h stays MALL-resident. bf16-copy path abandoned.
// R5: single-variable test of latency/MSHR-bound theory on the fp32 d_in
//     path: 16 rows in flight per wave (quarter-waves, 32 B/lane, 2-deep
//     unroll) vs R2's 2. If time doesn't move, 3.15 TB/s is the MALL random
//     ceiling and R2 was already at the byte floor.

constexpr int DIMS = 128;

__global__ __launch_bounds__(256, 6) void sine_predictor_kernel(
    const float* __restrict__ h,
    const int*   __restrict__ edges,   // [2, E] int32
    const float* __restrict__ W,       // [1, 128]
    const float* __restrict__ b,       // [1]
    float*       __restrict__ out,     // [2*E]: scores then mask
    int n_edges)
{
    const int lane    = threadIdx.x & 63;
    const int sub     = lane & 15;     // position within row: floats sub*8..sub*8+7
    const int quarter = lane >> 4;     // which of 4 consecutive edges
    const int wave_id = blockIdx.x * (blockDim.x >> 6) + (threadIdx.x >> 6);
    const int n_waves = gridDim.x * (blockDim.x >> 6);
    const int n_ch    = (n_edges + 3) >> 2;   // chunks of 4 edges (2 pairs)

    // W fragment for this lane's 8 elements.
    const float4 wl  = reinterpret_cast<const float4*>(W)[sub * 2 + 0];
    const float4 wh  = reinterpret_cast<const float4*>(W)[sub * 2 + 1];
    const float bias = b[0];

    for (int c = wave_id; c < n_ch; c += 2 * n_waves) {
        const int  c2   = c + n_waves;
        const bool has2 = c2 < n_ch;

        // ---- all index loads first (8 independent dword loads) ----
        const int eA  = 4 * c + quarter;
        const int eAc = min(eA, n_edges - 1);
        const int eB  = has2 ? 4 * c2 + quarter : eAc;
        const int eBc = min(eB, n_edges - 1);

        const int srcA = edges[eAc];
        const int objA = edges[n_edges + eAc];
        const int srcB = edges[eBc];
        const int objB = edges[n_edges + eBc];

        // ---- all 16 row-fragment loads (8 dwordx4 per lane, distinct regs) ----
        const float4* sAr = reinterpret_cast<const float4*>(h + (size_t)srcA * DIMS);
        const float4* oAr = reinterpret_cast<const float4*>(h + (size_t)objA * DIMS);
        const float4* sBr = reinterpret_cast<const float4*>(h + (size_t)srcB * DIMS);
        const float4* oBr = reinterpret_cast<const float4*>(h + (size_t)objB * DIMS);

        const float4 sA0 = sAr[sub * 2 + 0];
        const float4 sA1 = sAr[sub * 2 + 1];
        const float4 oA0 = oAr[sub * 2 + 0];
        const float4 oA1 = oAr[sub * 2 + 1];
        const float4 sB0 = sBr[sub * 2 + 0];
        const float4 sB1 = sBr[sub * 2 + 1];
        const float4 oB0 = oBr[sub * 2 + 0];
        const float4 oB1 = oBr[sub * 2 + 1];

        // ---- compute ----
        float xA = __sinf(sA0.x - oA0.x) * wl.x
                 + __sinf(sA0.y - oA0.y) * wl.y
                 + __sinf(sA0.z - oA0.z) * wl.z
                 + __sinf(sA0.w - oA0.w) * wl.w
                 + __sinf(sA1.x - oA1.x) * wh.x
                 + __sinf(sA1.y - oA1.y) * wh.y
                 + __sinf(sA1.z - oA1.z) * wh.z
                 + __sinf(sA1.w - oA1.w) * wh.w;
        float xB = __sinf(sB0.x - oB0.x) * wl.x
                 + __sinf(sB0.y - oB0.y) * wl.y
                 + __sinf(sB0.z - oB0.z) * wl.z
                 + __sinf(sB0.w - oB0.w) * wl.w
                 + __sinf(sB1.x - oB1.x) * wh.x
                 + __sinf(sB1.y - oB1.y) * wh.y
                 + __sinf(sB1.z - oB1.z) * wh.z
                 + __sinf(sB1.w - oB1.w) * wh.w;

        // ---- reduce within each 16-lane quarter ----
        #pragma unroll
        for (int m = 8; m >= 1; m >>= 1) xA += __shfl_xor(xA, m, 64);
        #pragma unroll
        for (int m = 8; m >= 1; m >>= 1) xB += __shfl_xor(xB, m, 64);
        xA += bias;
        xB += bias;

        // ---- pair softmax: partner quarter via xor lane 16 ----
        {
            const float other = __shfl_xor(xA, 16, 64);
            const float mx = fmaxf(xA, other);
            const float es = __expf(xA - mx);
            const float eo = __expf(other - mx);
            const float p  = es / (es + eo);
            if (sub == 0 && eA < n_edges) {
                out[eA]           = p;
                out[n_edges + eA] = (p > 0.5f) ? 1.0f : 0.0f;
            }
        }
        if (has2) {
            const float other = __shfl_xor(xB, 16, 64);
            const float mx = fmaxf(xB, other);
            const float es = __expf(xB - mx);
            const float eo = __expf(other - mx);
            const float p  = es / (es + eo);
            if (sub == 0 && eB < n_edges) {
                out[eB]           = p;
                out[n_edges + eB] = (p > 0.5f) ? 1.0f : 0.0f;
            }
        }
    }
}

extern "C" void kernel_launch(void* const* d_in, const int* in_sizes, int n_in,
                              void* d_out, int out_size, void* d_ws, size_t ws_size,
                              hipStream_t stream) {
    const float* h     = (const float*)d_in[0];
    const int*   edges = (const int*)d_in[1];
    const float* W     = (const float*)d_in[2];
    const float* b     = (const float*)d_in[3];
    float*       out   = (float*)d_out;

    const int n_edges = in_sizes[1] / 2;   // edges is [2, E]

    // __launch_bounds__(256,6): 6 waves/SIMD = 24 waves/CU = 6 blocks/CU.
    // Launch exactly the resident capacity (256 CU x 6 = 1536 blocks) so the
    // grid-stride loop has no serialized tail.
    const int blocks = 1536;
    sine_predictor_kernel<<<blocks, 256, 0, stream>>>(h, edges, W, b, out, n_edges);
}